// Round 22
// baseline (185.048 us; speedup 1.0000x reference)
//
#include <hip/hip_runtime.h>
#include <hip/hip_bf16.h>

#define NCLS 345
#define CPAD 384
#define DIM  512
#define BCAP 256

typedef float f32x4 __attribute__((ext_vector_type(4)));
typedef short s16x8 __attribute__((ext_vector_type(8)));
typedef unsigned long long u64;

__device__ __forceinline__ short f2bf(float f) {
  union { float f; unsigned u; } v; v.f = f;
  unsigned r = v.u + 0x7fffu + ((v.u >> 16) & 1u);   // RNE
  return (short)(r >> 16);
}

// ---- Stage 1: one pass over N, bucket (ent_bits<<32)|idx per class ----
__global__ __launch_bounds__(256) void scan_classes(
    const float* __restrict__ ent, const int* __restrict__ y_hat,
    u64* __restrict__ bucket, int* __restrict__ cnt, int N)
{
  int i = blockIdx.x * 256 + threadIdx.x;
  if (i >= N) return;
  int c = y_hat[i];
  unsigned eb = __float_as_uint(ent[i]);
  u64 key = ((u64)eb << 32) | (unsigned)i;
  int p = atomicAdd(&cnt[c], 1);
  if (p < BCAP) bucket[(size_t)c * BCAP + p] = key;
}

// ---- Stage 2: per-class select + normalized-row sum, emit FRAGMENT-PACKED W ----
// Packed: frag(kt 0..15, ct 0..23) of 1024B; lane = fq*16+fr holds
// W[col = ct*16+fr][k = kt*32+fq*8+j], j=0..7.
__global__ __launch_bounds__(512) void select_accum(
    const float* __restrict__ supports, const u64* __restrict__ bucket,
    const int* __restrict__ cnt, const int* __restrict__ fKp,
    short* __restrict__ Wp)
{
  const int c = blockIdx.x;
  const int tid = threadIdx.x;
  const int lane = tid & 63, w = tid >> 6;
  __shared__ u64   s_key[BCAP];
  __shared__ int   s_selidx[BCAP];
  __shared__ int   s_nsel;
  __shared__ float s_part[8][DIM];
  __shared__ float s_red[8];
  if (tid == 0) s_nsel = 0;
  const int S = (c < NCLS) ? min(cnt[c], BCAP) : 0;
  const int K = fKp[0];
  for (int e = tid; e < S; e += 512) s_key[e] = bucket[(size_t)c * BCAP + e];
  __syncthreads();
  for (int e = tid; e < S; e += 512) {
    u64 ke = s_key[e];
    int r = 0;
    for (int j = 0; j < S; ++j) r += (s_key[j] < ke) ? 1 : 0;
    if (r < K) { int p = atomicAdd(&s_nsel, 1); s_selidx[p] = (int)(unsigned)(ke & 0xffffffffull); }
  }
  __syncthreads();
  const int nsel = s_nsel;
  f32x4 p0 = {0.f,0.f,0.f,0.f}, p1 = {0.f,0.f,0.f,0.f};
  for (int e0 = w; e0 < nsel; e0 += 16) {
    const int e1 = e0 + 8;
    const bool h1 = (e1 < nsel);
    const f32x4* r0 = (const f32x4*)(supports + (size_t)s_selidx[e0] * DIM);
    f32x4 a0 = r0[lane], a1 = r0[lane + 64];
    f32x4 b0 = {0.f,0.f,0.f,0.f}, b1 = {0.f,0.f,0.f,0.f};
    if (h1) {
      const f32x4* r1 = (const f32x4*)(supports + (size_t)s_selidx[e1] * DIM);
      b0 = r1[lane]; b1 = r1[lane + 64];
    }
    float s0 = 0.f, s1 = 0.f;
#pragma unroll
    for (int j = 0; j < 4; ++j) {
      s0 = fmaf(a0[j], a0[j], s0); s0 = fmaf(a1[j], a1[j], s0);
      s1 = fmaf(b0[j], b0[j], s1); s1 = fmaf(b1[j], b1[j], s1);
    }
#pragma unroll
    for (int off = 32; off; off >>= 1) { s0 += __shfl_xor(s0, off); s1 += __shfl_xor(s1, off); }
    float c0 = 1.f / fmaxf(sqrtf(s0), 1e-12f);
    float c1 = 1.f / fmaxf(sqrtf(s1), 1e-12f);
#pragma unroll
    for (int j = 0; j < 4; ++j) { p0[j] = fmaf(a0[j], c0, p0[j]); p1[j] = fmaf(a1[j], c0, p1[j]); }
    if (h1) {
#pragma unroll
      for (int j = 0; j < 4; ++j) { p0[j] = fmaf(b0[j], c1, p0[j]); p1[j] = fmaf(b1[j], c1, p1[j]); }
    }
  }
  *(f32x4*)&s_part[w][lane * 4]       = p0;
  *(f32x4*)&s_part[w][256 + lane * 4] = p1;
  __syncthreads();
  float acc = 0.f;
#pragma unroll
  for (int ww = 0; ww < 8; ++ww) acc += s_part[ww][tid];
  float sq = acc * acc;
#pragma unroll
  for (int off = 32; off; off >>= 1) sq += __shfl_xor(sq, off);
  if (lane == 0) s_red[w] = sq;
  __syncthreads();
  float tot = 0.f;
#pragma unroll
  for (int ww = 0; ww < 8; ++ww) tot += s_red[ww];
  float sc = 1.f / fmaxf(sqrtf(tot), 1e-12f);
  {
    const int k = tid;
    const int kt = k >> 5, fq = (k >> 3) & 3, j = k & 7;
    const int ct = c >> 4, fr = c & 15;
    const size_t pos = (size_t)(kt * 24 + ct) * 512 + fq * 128 + fr * 8 + j;
    Wp[pos] = f2bf(acc * sc);
  }
}

// ---- Kernel B: PRODUCER/CONSUMER persistent GEMM ----
// 256 blocks x 512 thr, 128KB LDS (2x64KB A bufs). Waves 4-7 = producers:
// stage chunk ph (64 rows, R18 frag-linear layout) during phase ph.
// Waves 0-3 = consumers: compute chunk ph-1 (96 cols each, acc[4][6]) +
// direct NT stores. Antiphase -> HBM staging always overlaps compute/stores.
// One raw s_barrier + lgkmcnt(0) per phase; NT stores never drained.
__global__ __launch_bounds__(512, 2) void gemm_zw(
    const float* __restrict__ z, const short* __restrict__ Wp,
    float* __restrict__ out)
{
  __shared__ __align__(16) char lds[131072];     // 2 x 64KB A buffers
  const int tid  = threadIdx.x;
  const int lane = tid & 63;
  const int w    = tid >> 6;
  const int pw   = w & 3;                        // index within group
  const int fr   = lane & 15, fq = lane >> 4;
  const int Rbase = blockIdx.x * 256;            // 4 chunks of 64 rows

  // consumer B pointers: frag(kt, ct = pw*6+nt) at (kt*24+ct)*1024 + lane*16
  const char* pb = (const char*)Wp + (size_t)pw * 6 * 1024 + (size_t)lane * 16;

#pragma unroll 1
  for (int ph = 0; ph < 5; ++ph) {
    if (w >= 4) {
      if (ph < 4) {
        // ---- producer: stage chunk ph into buf ph&1 ----
        char* buf = lds + (size_t)(ph & 1) * 65536;
        const int Mb = Rbase + ph * 64;
#pragma unroll
        for (int i = 0; i < 16; ++i) {
          const int row = i * 4 + pw;
          const char* src = (const char*)(z + (size_t)(Mb + row) * DIM);
          f32x4 u0 = *(const f32x4*)(src + lane * 32);
          f32x4 u1 = *(const f32x4*)(src + lane * 32 + 16);
          s16x8 b;
#pragma unroll
          for (int j = 0; j < 4; ++j) { b[j] = f2bf(u0[j]); b[4 + j] = f2bf(u1[j]); }
          const int t  = lane >> 2, sfq = lane & 3;
          const int mt = row >> 4,  fr16 = row & 15;
          const unsigned slot = (unsigned)((sfq * 16 + fr16) ^ (t & 15));
          *(s16x8*)(buf + (size_t)(mt * 16 + t) * 1024 + slot * 16) = b;
        }
      }
    } else if (ph >= 1) {
      // ---- consumer: compute chunk ph-1 from buf (ph-1)&1 ----
      const int C = ph - 1;
      const char* pa = lds + (size_t)(C & 1) * 65536;
      const int Mb = Rbase + C * 64;
      f32x4 acc[4][6];
#pragma unroll
      for (int mt = 0; mt < 4; ++mt)
#pragma unroll
        for (int nt = 0; nt < 6; ++nt) acc[mt][nt] = f32x4{0.f, 0.f, 0.f, 0.f};
      s16x8 Bbuf[3][6];
#pragma unroll
      for (int s = 0; s < 2; ++s)
#pragma unroll
        for (int nt = 0; nt < 6; ++nt)
          Bbuf[s][nt] = *(const s16x8*)(pb + (size_t)s * 24576 + nt * 1024);
#pragma unroll
      for (int t = 0; t < 16; ++t) {
        if (t + 2 < 16) {
#pragma unroll
          for (int nt = 0; nt < 6; ++nt)
            Bbuf[(t + 2) % 3][nt] = *(const s16x8*)(pb + (size_t)(t + 2) * 24576 + nt * 1024);
        }
        const unsigned rslot = (unsigned)(((fq * 16 + fr) ^ (t & 15)) * 16);
        s16x8 af[4];
#pragma unroll
        for (int mt = 0; mt < 4; ++mt)
          af[mt] = *(const s16x8*)(pa + (size_t)(mt * 16 + t) * 1024 + rslot);
        __builtin_amdgcn_s_setprio(1);
#pragma unroll
        for (int nt = 0; nt < 6; ++nt)
#pragma unroll
          for (int mt = 0; mt < 4; ++mt)
            acc[mt][nt] = __builtin_amdgcn_mfma_f32_16x16x32_bf16(Bbuf[t % 3][nt], af[mt], acc[mt][nt], 0, 0, 0);
        __builtin_amdgcn_s_setprio(0);
      }
      // direct NT stores (stay in flight across the phase barrier)
#pragma unroll
      for (int mt = 0; mt < 4; ++mt) {
        const int row = Mb + mt * 16 + fr;
        float* prow = out + (size_t)row * NCLS;
#pragma unroll
        for (int nt = 0; nt < 6; ++nt) {
          const int colb = pw * 96 + nt * 16 + fq * 4;
          if (colb + 3 < NCLS) {
            f32x4 v = acc[mt][nt];
            __builtin_nontemporal_store(v[0], prow + colb);
            __builtin_nontemporal_store(v[1], prow + colb + 1);
            __builtin_nontemporal_store(v[2], prow + colb + 2);
            __builtin_nontemporal_store(v[3], prow + colb + 3);
          } else {
#pragma unroll
            for (int j = 0; j < 4; ++j)
              if (colb + j < NCLS) __builtin_nontemporal_store(acc[mt][nt][j], prow + colb + j);
          }
        }
      }
    }
    // phase boundary: LDS ordering only (producer ds_writes / consumer ds_reads)
    asm volatile("s_waitcnt lgkmcnt(0)" ::: "memory");
    __builtin_amdgcn_sched_barrier(0);
    __builtin_amdgcn_s_barrier();
  }
}

extern "C" void kernel_launch(void* const* d_in, const int* in_sizes, int n_in,
                              void* d_out, int out_size, void* d_ws, size_t ws_size,
                              hipStream_t stream) {
  const float* z        = (const float*)d_in[0];
  const float* supports = (const float*)d_in[1];
  const float* ent      = (const float*)d_in[2];
  const int*   y_hat    = (const int*)d_in[3];
  const int*   fK       = (const int*)d_in[4];
  float* out = (float*)d_out;
  short* Wp  = (short*)d_ws;           // fragment-packed W, 384 KB
  const int N = in_sizes[2];
  const int M = in_sizes[0] / DIM;

  const size_t offC = (size_t)CPAD * DIM * 2;          // 393216
  const size_t offB = offC + 2048;
  int* cnt    = (int*)((char*)d_ws + offC);
  u64* bucket = (u64*)((char*)d_ws + offB);
  hipMemsetAsync(cnt, 0, CPAD * sizeof(int), stream);
  scan_classes<<<dim3((N + 255) / 256), dim3(256), 0, stream>>>(ent, y_hat, bucket, cnt, N);
  select_accum<<<dim3(CPAD), dim3(512), 0, stream>>>(supports, bucket, cnt, fK, Wp);
  gemm_zw<<<dim3(M / 256), dim3(512), 0, stream>>>(z, Wp, out);
}